// Round 1
// baseline (56.631 us; speedup 1.0000x reference)
//
#include <hip/hip_runtime.h>

// Problem constants (from reference): B=64, S=512, D=1024, fp32 in/out.
#define BS 64
#define SS 512
#define DD 1024

__global__ __launch_bounds__(256) void merge_subword_kernel(
    const float* __restrict__ h,     // [B, S, D]
    const int*   __restrict__ wid,   // [B, S] sorted, contiguous word ids
    float*       __restrict__ out)   // [B, S, D]
{
    const int w = blockIdx.x;   // output position within row
    const int b = blockIdx.y;   // batch row

    const int* row = wid + b * SS;

    __shared__ int s_lo, s_hi, s_tot;
    if (threadIdx.x == 0) {
        int tot = row[SS - 1] + 1;   // sorted -> last element is the max
        s_tot = tot;
        if (w < tot) {
            // lower_bound(w): first t with row[t] >= w
            int lo = 0, hi = SS;
            while (lo < hi) {
                int m = (lo + hi) >> 1;
                if (row[m] < w) lo = m + 1; else hi = m;
            }
            s_lo = lo;
            // upper_bound(w): first t with row[t] > w
            int lo2 = lo, hi2 = SS;
            while (lo2 < hi2) {
                int m = (lo2 + hi2) >> 1;
                if (row[m] <= w) lo2 = m + 1; else hi2 = m;
            }
            s_hi = lo2;
        }
    }
    __syncthreads();

    const int tid = threadIdx.x;             // 256 threads x float4 = 1024 = D
    float4* dst = (float4*)(out + ((size_t)b * SS + w) * DD);

    if (w >= s_tot) {
        // passthrough: keep original values
        const float4* src = (const float4*)(h + ((size_t)b * SS + w) * DD);
        dst[tid] = src[tid];
    } else {
        const int lo = s_lo, hi = s_hi;
        const float inv = 1.0f / (float)(hi - lo);
        float4 acc = make_float4(0.f, 0.f, 0.f, 0.f);
        const float4* base = (const float4*)(h + ((size_t)b * SS + lo) * DD);
        const int nvec = DD / 4;
        for (int t = 0; t < hi - lo; ++t) {
            float4 v = base[(size_t)t * nvec + tid];
            acc.x += v.x; acc.y += v.y; acc.z += v.z; acc.w += v.w;
        }
        acc.x *= inv; acc.y *= inv; acc.z *= inv; acc.w *= inv;
        dst[tid] = acc;
    }
}

extern "C" void kernel_launch(void* const* d_in, const int* in_sizes, int n_in,
                              void* d_out, int out_size, void* d_ws, size_t ws_size,
                              hipStream_t stream) {
    (void)in_sizes; (void)n_in; (void)out_size; (void)d_ws; (void)ws_size;
    const float* h   = (const float*)d_in[0];
    const int*   wid = (const int*)d_in[1];
    float*       out = (float*)d_out;

    dim3 grid(SS, BS);   // one block per (w, b) output row
    dim3 block(256);
    merge_subword_kernel<<<grid, block, 0, stream>>>(h, wid, out);
}